// Round 1
// 1386.769 us; speedup vs baseline: 1.0549x; 1.0549x over previous
//
#include <hip/hip_runtime.h>
#include <hip/hip_fp16.h>
#include <math.h>

// Problem constants
#define ROWS   8192        // B*L = 2*4096
#define DIMK   2048
#define HIDN   4096
#define QCH    128
#define NCHUNK 32          // L/Q per batch

typedef __attribute__((ext_vector_type(8))) short short8;
typedef __attribute__((ext_vector_type(8))) _Float16 half8;
typedef __attribute__((ext_vector_type(4))) float floatx4;

static __device__ inline unsigned short f2h(float f){
  union { _Float16 h; unsigned short u; } v; v.h = (_Float16)f; return v.u;
}
static __device__ inline float h2f(unsigned short u){
  union { unsigned short u; _Float16 h; } v; v.u = u; return (float)v.h;
}
static __device__ inline void async_cp16(const void* g, void* l){
  __builtin_amdgcn_global_load_lds((const __attribute__((address_space(1))) void*)g,
                                   (__attribute__((address_space(3))) void*)l, 16, 0, 0);
}

// ---------------- cast fp32 -> fp16 (packed x4) ----------------
__global__ void k_cast(const float* __restrict__ in, unsigned short* __restrict__ out, int n4){
  int i = blockIdx.x * 256 + threadIdx.x;
  if (i < n4){
    float4 v = ((const float4*)in)[i];
    unsigned long long p = (unsigned long long)f2h(v.x)
                         | ((unsigned long long)f2h(v.y) << 16)
                         | ((unsigned long long)f2h(v.z) << 32)
                         | ((unsigned long long)f2h(v.w) << 48);
    ((unsigned long long*)out)[i] = p;
  }
}

// ---------------- exact fp32 dt_raw = x @ W_in[8448:8512].T ----------------
// 256 blocks x 32 rows. Wave w owns rows r0+8w..r0+8w+7 (uniform -> broadcast x loads).
// W tile (64x128 fp32) staged in LDS, coalesced, padded stride 132 (bank-spread).
#define DT_KT 128
__global__ __launch_bounds__(256)
void k_dtraw(const float* __restrict__ x, const float* __restrict__ Win,
             float* __restrict__ dtraw){
  __shared__ float ws[64 * (DT_KT + 4)];          // stride 132 floats
  const int t = threadIdx.x;
  const int lane = t & 63, w = t >> 6;
  const int r0 = blockIdx.x * 32;
  const int rw = __builtin_amdgcn_readfirstlane(r0 + w * 8);
  float acc[8] = {};
  for (int k0 = 0; k0 < DIMK; k0 += DT_KT){
    __syncthreads();                              // previous tile's reads done
#pragma unroll
    for (int l = 0; l < 8; l++){
      int fidx = (l * 256 + t) * 4;               // 0..8191 floats
      int row = fidx >> 7, col = fidx & 127;
      *(float4*)&ws[row * 132 + col] =
          *(const float4*)&Win[(size_t)(8448 + row) * DIMK + k0 + col];
    }
    __syncthreads();
#pragma unroll 4
    for (int kk = 0; kk < DT_KT; kk += 4){
      float4 wv = *(const float4*)&ws[lane * 132 + kk];
#pragma unroll
      for (int i = 0; i < 8; i++){
        float4 xv = *(const float4*)&x[(size_t)(rw + i) * DIMK + k0 + kk];
        acc[i] += wv.x*xv.x + wv.y*xv.y + wv.z*xv.z + wv.w*xv.w;
      }
    }
  }
#pragma unroll
  for (int i = 0; i < 8; i++)
    dtraw[(size_t)(rw + i) * 64 + lane] = acc[i];
}

// ---------------- shared MFMA GEMM core: acc += A[M,K] @ B[N,K]^T tile ----------------
__device__ inline void gemm_core(const unsigned short* __restrict__ A,
                                 const unsigned short* __restrict__ B,
                                 int Kd, int row0, int col0,
                                 unsigned short* lA, unsigned short* lB,
                                 floatx4 (&acc)[4][4], int t){
  const int w = t >> 6, lane = t & 63;
  const int quad = lane >> 4, l16 = lane & 15;
  const int wr = (w >> 1) * 64, wc = (w & 1) * 64;
  for (int k0 = 0; k0 < Kd; k0 += 64){
#pragma unroll
    for (int i = 0; i < 4; i++){
      int cb = i * 256 + w * 64, c = cb + lane;
      async_cp16(A + (size_t)(row0 + (c >> 3)) * Kd + k0 + (c & 7) * 8, lA + (size_t)cb * 8);
    }
#pragma unroll
    for (int i = 0; i < 4; i++){
      int cb = i * 256 + w * 64, c = cb + lane;
      async_cp16(B + (size_t)(col0 + (c >> 3)) * Kd + k0 + (c & 7) * 8, lB + (size_t)cb * 8);
    }
    __syncthreads();
#pragma unroll
    for (int ks = 0; ks < 2; ks++){
      half8 af[4], bfr[4];
#pragma unroll
      for (int i = 0; i < 4; i++){
        af[i]  = *(const half8*)&lA[(wr + i*16 + l16)*64 + ks*32 + quad*8];
        bfr[i] = *(const half8*)&lB[(wc + i*16 + l16)*64 + ks*32 + quad*8];
      }
#pragma unroll
      for (int i = 0; i < 4; i++)
#pragma unroll
        for (int j = 0; j < 4; j++)
          acc[i][j] = __builtin_amdgcn_mfma_f32_16x16x32_f16(af[i], bfr[j], acc[i][j], 0, 0, 0);
    }
    __syncthreads();
  }
}

// ---------------- GEMM1: routed fp16 epilogue (z | xs | bc) ----------------
__global__ __launch_bounds__(256, 2)
void k_gemm1(const unsigned short* __restrict__ A, const unsigned short* __restrict__ B,
             unsigned short* __restrict__ zbuf, unsigned short* __restrict__ xsraw,
             unsigned short* __restrict__ bcraw){
  __shared__ __align__(16) unsigned short lA[128*64];
  __shared__ __align__(16) unsigned short lB[128*64];
  const int t = threadIdx.x;
  const int row0 = blockIdx.y * 128, col0 = blockIdx.x * 128;
  floatx4 acc[4][4] = {};
  gemm_core(A, B, DIMK, row0, col0, lA, lB, acc, t);
  const int w = t >> 6, lane = t & 63, quad = lane >> 4, l16 = lane & 15;
  const int wr = (w >> 1) * 64, wc = (w & 1) * 64;
  unsigned short* dst; int cbase, ldd;
  if (col0 < 4096){ dst = zbuf; cbase = 0; ldd = 4096; }
  else if (col0 < 8192){ dst = xsraw; cbase = 4096; ldd = 4096; }
  else { dst = bcraw; cbase = 8192; ldd = 256; }
#pragma unroll
  for (int i = 0; i < 4; i++)
#pragma unroll
    for (int j = 0; j < 4; j++){
      int rb = row0 + wr + i*16 + quad*4;
      int cc = col0 + wc + j*16 + l16 - cbase;
#pragma unroll
      for (int r = 0; r < 4; r++)
        dst[(size_t)(rb + r) * ldd + cc] = f2h(acc[i][j][r]);
    }
}

// ---------------- GEMM2: fp32 epilogue to d_out ----------------
__global__ __launch_bounds__(256, 2)
void k_gemm2(const unsigned short* __restrict__ A, const unsigned short* __restrict__ B,
             float* __restrict__ C){
  __shared__ __align__(16) unsigned short lA[128*64];
  __shared__ __align__(16) unsigned short lB[128*64];
  const int t = threadIdx.x;
  const int row0 = blockIdx.y * 128, col0 = blockIdx.x * 128;
  floatx4 acc[4][4] = {};
  gemm_core(A, B, HIDN, row0, col0, lA, lB, acc, t);
  const int w = t >> 6, lane = t & 63, quad = lane >> 4, l16 = lane & 15;
  const int wr = (w >> 1) * 64, wc = (w & 1) * 64;
#pragma unroll
  for (int i = 0; i < 4; i++)
#pragma unroll
    for (int j = 0; j < 4; j++){
      int rb = row0 + wr + i*16 + quad*4;
      int cc = col0 + wc + j*16 + l16;
#pragma unroll
      for (int r = 0; r < 4; r++)
        C[(size_t)(rb + r) * DIMK + cc] = acc[i][j][r];
    }
}

// ---------------- extract pre-conv xs halo rows (3 per chunk boundary) ----------------
// slot s holds row bc*128 - 3 + s
__global__ void k_halo(const unsigned short* __restrict__ xsraw, unsigned short* __restrict__ halo){
  int col = blockIdx.x * 256 + threadIdx.x;   // [0,4096)
  int slot = blockIdx.y, bc = blockIdx.z;
  long r = (long)bc * QCH - 3 + slot;
  if (r >= 0)
    halo[((size_t)bc * 3 + slot) * 4096 + col] = xsraw[(size_t)r * 4096 + col];
}

// ---------------- causal conv (K=4) + SiLU on B/C columns only ----------------
__global__ void k_convbc(const unsigned short* __restrict__ bcraw, const float* __restrict__ cw,
                         unsigned short* __restrict__ bcc){
  int row = blockIdx.x, c = threadIdx.x;      // c in [0,256)
  int tl = row & 4095;
  const float4 wv = *(const float4*)&cw[(size_t)(4096 + c) * 4];
  const unsigned short* col = bcraw + c;
  size_t rb = (size_t)row * 256;
  float a = h2f(col[rb]) * wv.w;
  if (tl >= 1) a += h2f(col[rb - 256]) * wv.z;
  if (tl >= 2) a += h2f(col[rb - 512]) * wv.y;
  if (tl >= 3) a += h2f(col[rb - 768]) * wv.x;
  bcc[rb + c] = f2h(a / (1.f + __expf(-a)));
}

// ---------------- softplus(dt) + per-chunk cumsum of dt*A ----------------
__global__ void k_dtcum(const float* __restrict__ dtraw, const float* __restrict__ dtbias,
                        const float* __restrict__ Alog, float* __restrict__ dtb,
                        float* __restrict__ cumb){
  int bc = blockIdx.x;        // [0,64)
  int h  = threadIdx.x;       // [0,64)
  float bias = dtbias[h];
  float A = -__expf(Alog[h]);
  float run = 0.f;
  size_t rowb = (size_t)bc * QCH;
  for (int q = 0; q < QCH; q++){
    float dr = dtraw[(rowb + q) * 64 + h] + bias;
    float dt = dr > 20.f ? dr : log1pf(__expf(dr));
    dtb[(rowb + q) * 64 + h] = dt;
    run += dt * A;
    cumb[(rowb + q) * 64 + h] = run;
  }
}

// ---------------- fused conv+SiLU staging of xs tile, transposed (P x Q) ----------------
// tap t-k, row rowb+q-k: in-chunk if q>=k, else halo slot (q-k+3)
__device__ inline void stage_xsT(const unsigned short* __restrict__ xsraw,
                                 const unsigned short* __restrict__ halo,
                                 const float* cws, unsigned short* xsT,
                                 int bc, int h, int t){
  const size_t rowb = (size_t)bc * QCH;
  const int tl0 = (bc & 31) * QCH;
#pragma unroll
  for (int it = 0; it < 2; it++){
    int idx = it * 256 + t;
    int q = idx & 127, p0 = (idx >> 7) * 16;
    int tl = tl0 + q;
    const unsigned short* cur = xsraw + (rowb + q) * 4096 + h * 64 + p0;
    const unsigned short* hb  = halo + ((size_t)bc * 3) * 4096 + h * 64 + p0;
    const unsigned short* r1 = (q >= 1) ? cur - 4096     : hb + 2 * 4096;
    const unsigned short* r2 = (q >= 2) ? cur - 2 * 4096 : hb + (size_t)(q + 1) * 4096;
    const unsigned short* r3 = (q >= 3) ? cur - 3 * 4096 : hb + (size_t)q * 4096;
    float f1 = (tl >= 1) ? 1.f : 0.f;
    float f2 = (tl >= 2) ? 1.f : 0.f;
    float f3 = (tl >= 3) ? 1.f : 0.f;
    short8 c0 = *(const short8*)cur, c1 = *(const short8*)(cur + 8);
    short8 a0 = *(const short8*)r1,  a1 = *(const short8*)(r1 + 8);
    short8 b0 = *(const short8*)r2,  b1 = *(const short8*)(r2 + 8);
    short8 d0 = *(const short8*)r3,  d1 = *(const short8*)(r3 + 8);
#pragma unroll
    for (int j = 0; j < 16; j++){
      int col = p0 + j;
      const float* wp = cws + col * 4;
      float vc = h2f((unsigned short)(j < 8 ? c0[j] : c1[j-8]));
      float v1 = h2f((unsigned short)(j < 8 ? a0[j] : a1[j-8]));
      float v2 = h2f((unsigned short)(j < 8 ? b0[j] : b1[j-8]));
      float v3 = h2f((unsigned short)(j < 8 ? d0[j] : d1[j-8]));
      float a = vc * wp[3] + f1 * v1 * wp[2] + f2 * v2 * wp[1] + f3 * v3 * wp[0];
      float s = a / (1.f + __expf(-a));
      xsT[col * 128 + q] = f2h(s);
    }
  }
}

// ---------------- per-(chunk,head): CB -> M -> Yd; + Yoff from Sprev; y = Yd+Yoff+D*xs ----------------
__global__ __launch_bounds__(256, 2)
void k_chunk1(const unsigned short* __restrict__ xsraw, const unsigned short* __restrict__ bcc,
              const unsigned short* __restrict__ halo, const float* __restrict__ cw,
              const float* __restrict__ dtb, const float* __restrict__ cumb,
              const float* __restrict__ Dp, const unsigned short* __restrict__ st,
              unsigned short* __restrict__ ybuf){
  __shared__ __align__(16) unsigned short Ml[128*128];
  __shared__ __align__(16) unsigned short xsT[64*128];
  __shared__ float cum_s[128], dt_s[128];
  __shared__ float cws[64*4];
  const int blk = blockIdx.x, h = blk & 63, bc = blk >> 6;
  const size_t rowb = (size_t)bc * QCH;
  const int t = threadIdx.x, w = t >> 6, lane = t & 63, quad = lane >> 4, l16 = lane & 15;
  const int wrow = w * 32;
  if (t < 128){ cum_s[t] = cumb[(rowb + t)*64 + h]; dt_s[t] = dtb[(rowb + t)*64 + h]; }
  if (t < 64) *(float4*)&cws[t*4] = *(const float4*)&cw[((size_t)h*64 + t)*4];
  __syncthreads();
  stage_xsT(xsraw, halo, cws, xsT, bc, h, t);
  // CB = C @ B^T from post-conv bcc
  floatx4 acc[2][8] = {};
  const unsigned short* Cb = bcc + rowb * 256 + 128;
  const unsigned short* Bb = bcc + rowb * 256;
#pragma unroll
  for (int ks = 0; ks < 4; ks++){
    half8 af[2];
#pragma unroll
    for (int i = 0; i < 2; i++)
      af[i] = *(const half8*)(Cb + (size_t)(wrow + i*16 + l16) * 256 + ks*32 + quad*8);
#pragma unroll
    for (int j = 0; j < 8; j++){
      half8 bfr = *(const half8*)(Bb + (size_t)(j*16 + l16) * 256 + ks*32 + quad*8);
#pragma unroll
      for (int i = 0; i < 2; i++)
        acc[i][j] = __builtin_amdgcn_mfma_f32_16x16x32_f16(af[i], bfr, acc[i][j], 0, 0, 0);
    }
  }
  // M = CB * exp(cum_i - cum_j) * dt_j, causal, -> LDS fp16
#pragma unroll
  for (int i = 0; i < 2; i++)
#pragma unroll
    for (int j = 0; j < 8; j++){
      int jc = j*16 + l16;
      float dtj = dt_s[jc], cj = cum_s[jc];
#pragma unroll
      for (int r = 0; r < 4; r++){
        int ir = wrow + i*16 + quad*4 + r;
        float m = (ir >= jc) ? acc[i][j][r] * __expf(cum_s[ir] - cj) * dtj : 0.f;
        Ml[ir * 128 + jc] = f2h(m);
      }
    }
  __syncthreads();
  // Yd = M @ xs
  floatx4 accY[2][4] = {};
#pragma unroll
  for (int ks = 0; ks < 4; ks++){
    half8 af[2], bfr[4];
#pragma unroll
    for (int i = 0; i < 2; i++)
      af[i] = *(const half8*)&Ml[(wrow + i*16 + l16)*128 + ks*32 + quad*8];
#pragma unroll
    for (int p = 0; p < 4; p++)
      bfr[p] = *(const half8*)&xsT[(p*16 + l16)*128 + ks*32 + quad*8];
#pragma unroll
    for (int i = 0; i < 2; i++)
#pragma unroll
      for (int p = 0; p < 4; p++)
        accY[i][p] = __builtin_amdgcn_mfma_f32_16x16x32_f16(af[i], bfr[p], accY[i][p], 0, 0, 0);
  }
  // ---- Yoff: stage Sprev (fp16) into Ml's LDS, then C @ Sprev^T ----
  __syncthreads();                       // all Yd reads of Ml done
  unsigned short* Sp = Ml;               // reuse (64*128 <= 128*128)
  {
    size_t base = ((size_t)bc * 64 + h) * 8192;
#pragma unroll
    for (int it = 0; it < 4; it++){
      int idx = (it * 256 + t) * 8;
      *(short8*)&Sp[idx] = *(const short8*)&st[base + idx];
    }
  }
  __syncthreads();
  floatx4 accO[2][4] = {};
#pragma unroll
  for (int ks = 0; ks < 4; ks++){
    half8 af[2], bfr[4];
#pragma unroll
    for (int i = 0; i < 2; i++)
      af[i] = *(const half8*)(Cb + (size_t)(wrow + i*16 + l16) * 256 + ks*32 + quad*8);
#pragma unroll
    for (int p = 0; p < 4; p++)
      bfr[p] = *(const half8*)&Sp[(p*16 + l16)*128 + ks*32 + quad*8];
#pragma unroll
    for (int i = 0; i < 2; i++)
#pragma unroll
      for (int p = 0; p < 4; p++)
        accO[i][p] = __builtin_amdgcn_mfma_f32_16x16x32_f16(af[i], bfr[p], accO[i][p], 0, 0, 0);
  }
  float Dh = Dp[h];
#pragma unroll
  for (int i = 0; i < 2; i++)
#pragma unroll
    for (int p = 0; p < 4; p++){
      int pc = p*16 + l16;
#pragma unroll
      for (int r = 0; r < 4; r++){
        int ir = wrow + i*16 + quad*4 + r;
        float y = accY[i][p][r] + __expf(cum_s[ir]) * accO[i][p][r] + Dh * h2f(xsT[pc*128 + ir]);
        ybuf[(rowb + ir) * (size_t)HIDN + h*64 + pc] = f2h(y);
      }
    }
}

// ---------------- per-(chunk,head): states[p][n] = sum_q xs[q][p]*wdec_q*B[q][n] ----------------
__global__ __launch_bounds__(256, 2)
void k_chunk2(const unsigned short* __restrict__ xsraw, const unsigned short* __restrict__ bcc,
              const unsigned short* __restrict__ halo, const float* __restrict__ cw,
              const float* __restrict__ dtb, const float* __restrict__ cumb,
              unsigned short* __restrict__ st){
  __shared__ __align__(16) unsigned short wBT[128*128];
  __shared__ __align__(16) unsigned short xsT[64*128];
  __shared__ float cum_s[128], dt_s[128];
  __shared__ float cws[64*4];
  const int blk = blockIdx.x, h = blk & 63, bc = blk >> 6;
  const size_t rowb = (size_t)bc * QCH;
  const int t = threadIdx.x, w = t >> 6, lane = t & 63, quad = lane >> 4, l16 = lane & 15;
  if (t < 128){ cum_s[t] = cumb[(rowb + t)*64 + h]; dt_s[t] = dtb[(rowb + t)*64 + h]; }
  if (t < 64) *(float4*)&cws[t*4] = *(const float4*)&cw[((size_t)h*64 + t)*4];
  __syncthreads();
  stage_xsT(xsraw, halo, cws, xsT, bc, h, t);
  float clast = cum_s[127];
#pragma unroll
  for (int it = 0; it < 2; it++){                 // wBT[n][q] = B[q][n]*wdec_q
    int idx = it * 256 + t;
    int q = idx & 127, n0 = (idx >> 7) * 32;
    float wd = __expf(clast - cum_s[q]) * dt_s[q];
    const unsigned short* gp = bcc + (rowb + q) * 256 + n0;
#pragma unroll
    for (int c4 = 0; c4 < 4; c4++){
      short8 v = *(const short8*)(gp + c4*8);
#pragma unroll
      for (int jj = 0; jj < 8; jj++)
        wBT[(n0 + c4*8 + jj)*128 + q] = f2h(h2f((unsigned short)v[jj]) * wd);
    }
  }
  __syncthreads();
  floatx4 acc[8] = {};
#pragma unroll
  for (int ks = 0; ks < 4; ks++){
    half8 af = *(const half8*)&xsT[(w*16 + l16)*128 + ks*32 + quad*8];
#pragma unroll
    for (int j = 0; j < 8; j++){
      half8 bfr = *(const half8*)&wBT[(j*16 + l16)*128 + ks*32 + quad*8];
      acc[j] = __builtin_amdgcn_mfma_f32_16x16x32_f16(af, bfr, acc[j], 0, 0, 0);
    }
  }
  size_t base = ((size_t)bc * 64 + h) * 8192;
#pragma unroll
  for (int j = 0; j < 8; j++){
    int n = j*16 + l16;
#pragma unroll
    for (int r = 0; r < 4; r++){
      int p = w*16 + quad*4 + r;
      st[base + p*128 + n] = f2h(acc[j][r]);
    }
  }
}

// ---------------- sequential inter-chunk scan (fp16 states -> Sprev, in place) ----------------
__global__ void k_scan(unsigned short* __restrict__ st, const float* __restrict__ cumb){
  int id = blockIdx.x * 256 + threadIdx.x;  // [0, 2*64*64*128)
  int n = id & 127, p = (id >> 7) & 63, h = (id >> 13) & 63, b = id >> 19;
  float S = 0.f;
  for (int c = 0; c < NCHUNK; c++){
    int bc = b * NCHUNK + c;
    size_t idx = ((size_t)bc * 64 + h) * 8192 + (size_t)p * 128 + n;
    float dec = __expf(cumb[((size_t)bc * QCH + 127) * 64 + h]);
    float v = h2f(st[idx]);
    st[idx] = f2h(S);
    S = S * dec + v;
  }
}

// ---------------- gate y*silu(z) + RMSNorm, in-place fp16 ----------------
__global__ __launch_bounds__(256)
void k_gate(unsigned short* __restrict__ yb, const unsigned short* __restrict__ zb,
            const float* __restrict__ nw){
  __shared__ float red[4];
  int row = blockIdx.x, t = threadIdx.x;
  float vals[16], ss = 0.f;
#pragma unroll
  for (int it = 0; it < 16; it++){
    int c = it * 256 + t;
    float y = h2f(yb[(size_t)row * HIDN + c]);
    float z = h2f(zb[(size_t)row * HIDN + c]);
    float v = y * (z / (1.f + __expf(-z)));
    vals[it] = v; ss += v * v;
  }
  for (int o = 32; o > 0; o >>= 1) ss += __shfl_down(ss, o, 64);
  int w = t >> 6, lane = t & 63;
  if (lane == 0) red[w] = ss;
  __syncthreads();
  float scale = rsqrtf((red[0] + red[1] + red[2] + red[3]) / (float)HIDN + 1e-5f);
#pragma unroll
  for (int it = 0; it < 16; it++){
    int c = it * 256 + t;
    yb[(size_t)row * HIDN + c] = f2h(vals[it] * scale * nw[c]);
  }
}

extern "C" void kernel_launch(void* const* d_in, const int* in_sizes, int n_in,
                              void* d_out, int out_size, void* d_ws, size_t ws_size,
                              hipStream_t stream){
  const float* x      = (const float*)d_in[0];
  const float* Win    = (const float*)d_in[1];
  const float* convw  = (const float*)d_in[2];
  const float* dtbias = (const float*)d_in[3];
  const float* Alog   = (const float*)d_in[4];
  const float* Dp     = (const float*)d_in[5];
  const float* nw     = (const float*)d_in[6];
  const float* Wout   = (const float*)d_in[7];
  float* out = (float*)d_out;

  char* ws = (char*)d_ws;
  size_t off = 0;
  auto alloc = [&](size_t bytes)->void*{ void* p = ws + off; off += (bytes + 255) & ~(size_t)255; return p; };
  unsigned short* xw    = (unsigned short*)alloc((size_t)ROWS * DIMK * 2);   // 33.5 MB (dead after gemm1)
  unsigned short* winb  = (unsigned short*)alloc((size_t)8448 * DIMK * 2);   // 34.6 MB (dead after gemm1)
  float*          dtraw = (float*)alloc((size_t)ROWS * 64 * 4);              // 2.1 MB
  unsigned short* woutb = (unsigned short*)alloc((size_t)DIMK * HIDN * 2);   // 16.8 MB
  unsigned short* zbuf  = (unsigned short*)alloc((size_t)ROWS * HIDN * 2);   // 67.1 MB
  unsigned short* xsraw = (unsigned short*)alloc((size_t)ROWS * HIDN * 2);   // 67.1 MB (becomes ybuf/yn)
  unsigned short* bcraw = (unsigned short*)alloc((size_t)ROWS * 256 * 2);    // 4.2 MB
  unsigned short* bcc   = (unsigned short*)alloc((size_t)ROWS * 256 * 2);    // 4.2 MB
  unsigned short* halo  = (unsigned short*)alloc((size_t)64 * 3 * 4096 * 2); // 1.5 MB
  float*          dtb   = (float*)alloc((size_t)ROWS * 64 * 4);              // 2.1 MB
  float*          cumb  = (float*)alloc((size_t)ROWS * 64 * 4);              // 2.1 MB
  // total ~224.5 MiB; states (fp16, 67.1 MB) overlays dead xw+winb region
  unsigned short* st    = xw;
  unsigned short* ybuf  = xsraw;   // chunk1 writes y in-place over pre-conv xs (chunk2 ran first)

  k_cast<<<(ROWS*DIMK/4 + 255)/256, 256, 0, stream>>>(x, xw, ROWS*DIMK/4);
  k_cast<<<(8448*DIMK/4 + 255)/256, 256, 0, stream>>>(Win, winb, 8448*DIMK/4);
  k_cast<<<(DIMK*HIDN/4 + 255)/256, 256, 0, stream>>>(Wout, woutb, DIMK*HIDN/4);
  k_dtraw<<<ROWS/32, 256, 0, stream>>>(x, Win, dtraw);
  k_gemm1<<<dim3(66, ROWS/128), 256, 0, stream>>>(xw, winb, zbuf, xsraw, bcraw);
  k_halo<<<dim3(16, 3, 64), 256, 0, stream>>>(xsraw, halo);
  k_convbc<<<ROWS, 256, 0, stream>>>(bcraw, convw, bcc);
  k_dtcum<<<64, 64, 0, stream>>>(dtraw, dtbias, Alog, dtb, cumb);
  k_chunk2<<<4096, 256, 0, stream>>>(xsraw, bcc, halo, convw, dtb, cumb, st);
  k_scan<<<4096, 256, 0, stream>>>(st, cumb);
  k_chunk1<<<4096, 256, 0, stream>>>(xsraw, bcc, halo, convw, dtb, cumb, Dp, st, ybuf);
  k_gate<<<ROWS, 256, 0, stream>>>(ybuf, zbuf, nw);
  k_gemm2<<<dim3(16, ROWS/128), 256, 0, stream>>>(ybuf, woutb, out);
}

// Round 2
// 1185.816 us; speedup vs baseline: 1.2336x; 1.1695x over previous
//
#include <hip/hip_runtime.h>
#include <hip/hip_fp16.h>
#include <math.h>

// Problem constants
#define ROWS   8192        // B*L = 2*4096
#define DIMK   2048
#define HIDN   4096
#define QCH    128
#define NCHUNK 32          // L/Q per batch

typedef __attribute__((ext_vector_type(8))) short short8;
typedef __attribute__((ext_vector_type(8))) _Float16 half8;
typedef __attribute__((ext_vector_type(4))) float floatx4;

static __device__ inline unsigned short f2h(float f){
  union { _Float16 h; unsigned short u; } v; v.h = (_Float16)f; return v.u;
}
static __device__ inline float h2f(unsigned short u){
  union { unsigned short u; _Float16 h; } v; v.u = u; return (float)v.h;
}
static __device__ inline void async_cp16(const void* g, void* l){
  __builtin_amdgcn_global_load_lds((const __attribute__((address_space(1))) void*)g,
                                   (__attribute__((address_space(3))) void*)l, 16, 0, 0);
}

// ---------------- cast fp32 -> fp16 (packed x4) ----------------
__global__ void k_cast(const float* __restrict__ in, unsigned short* __restrict__ out, int n4){
  int i = blockIdx.x * 256 + threadIdx.x;
  if (i < n4){
    float4 v = ((const float4*)in)[i];
    unsigned long long p = (unsigned long long)f2h(v.x)
                         | ((unsigned long long)f2h(v.y) << 16)
                         | ((unsigned long long)f2h(v.z) << 32)
                         | ((unsigned long long)f2h(v.w) << 48);
    ((unsigned long long*)out)[i] = p;
  }
}

// ---------------- exact fp32 dt_raw = x @ W_in[8448:8512].T ----------------
// 1024 blocks x 8 rows; wave w owns rows r0+2w, r0+2w+1 (uniform -> broadcast x loads).
// W tile (64x128 fp32) staged in LDS (33 KB) -> 4 blocks/CU = 4 waves/SIMD to hide
// ds_read/s_load latency (round-1 version had 1 wave/SIMD and was latency-bound).
#define DT_KT 128
__global__ __launch_bounds__(256)
void k_dtraw(const float* __restrict__ x, const float* __restrict__ Win,
             float* __restrict__ dtraw){
  __shared__ float ws[64 * (DT_KT + 4)];          // stride 132 floats
  const int t = threadIdx.x;
  const int lane = t & 63, w = t >> 6;
  const int r0 = blockIdx.x * 8;
  const int rw = __builtin_amdgcn_readfirstlane(r0 + w * 2);
  float acc0 = 0.f, acc1 = 0.f;
  for (int k0 = 0; k0 < DIMK; k0 += DT_KT){
    __syncthreads();                              // previous tile's reads done
#pragma unroll
    for (int l = 0; l < 8; l++){
      int fidx = (l * 256 + t) * 4;               // 0..8191 floats
      int row = fidx >> 7, col = fidx & 127;
      *(float4*)&ws[row * 132 + col] =
          *(const float4*)&Win[(size_t)(8448 + row) * DIMK + k0 + col];
    }
    __syncthreads();
    const float* xa = x + (size_t)rw * DIMK + k0;
    const float* xb = xa + DIMK;
#pragma unroll 8
    for (int kk = 0; kk < DT_KT; kk += 4){
      float4 wv = *(const float4*)&ws[lane * 132 + kk];
      float4 va = *(const float4*)&xa[kk];
      float4 vb = *(const float4*)&xb[kk];
      acc0 += wv.x*va.x + wv.y*va.y + wv.z*va.z + wv.w*va.w;
      acc1 += wv.x*vb.x + wv.y*vb.y + wv.z*vb.z + wv.w*vb.w;
    }
  }
  dtraw[(size_t)rw * 64 + lane]       = acc0;
  dtraw[(size_t)(rw + 1) * 64 + lane] = acc1;
}

// ---------------- shared MFMA GEMM core: acc += A[M,K] @ B[N,K]^T tile ----------------
__device__ inline void gemm_core(const unsigned short* __restrict__ A,
                                 const unsigned short* __restrict__ B,
                                 int Kd, int row0, int col0,
                                 unsigned short* lA, unsigned short* lB,
                                 floatx4 (&acc)[4][4], int t){
  const int w = t >> 6, lane = t & 63;
  const int quad = lane >> 4, l16 = lane & 15;
  const int wr = (w >> 1) * 64, wc = (w & 1) * 64;
  for (int k0 = 0; k0 < Kd; k0 += 64){
#pragma unroll
    for (int i = 0; i < 4; i++){
      int cb = i * 256 + w * 64, c = cb + lane;
      async_cp16(A + (size_t)(row0 + (c >> 3)) * Kd + k0 + (c & 7) * 8, lA + (size_t)cb * 8);
    }
#pragma unroll
    for (int i = 0; i < 4; i++){
      int cb = i * 256 + w * 64, c = cb + lane;
      async_cp16(B + (size_t)(col0 + (c >> 3)) * Kd + k0 + (c & 7) * 8, lB + (size_t)cb * 8);
    }
    __syncthreads();
#pragma unroll
    for (int ks = 0; ks < 2; ks++){
      half8 af[4], bfr[4];
#pragma unroll
      for (int i = 0; i < 4; i++){
        af[i]  = *(const half8*)&lA[(wr + i*16 + l16)*64 + ks*32 + quad*8];
        bfr[i] = *(const half8*)&lB[(wc + i*16 + l16)*64 + ks*32 + quad*8];
      }
#pragma unroll
      for (int i = 0; i < 4; i++)
#pragma unroll
        for (int j = 0; j < 4; j++)
          acc[i][j] = __builtin_amdgcn_mfma_f32_16x16x32_f16(af[i], bfr[j], acc[i][j], 0, 0, 0);
    }
    __syncthreads();
  }
}

// ---------------- GEMM1: routed fp16 epilogue (z | xs | bc) ----------------
__global__ __launch_bounds__(256, 2)
void k_gemm1(const unsigned short* __restrict__ A, const unsigned short* __restrict__ B,
             unsigned short* __restrict__ zbuf, unsigned short* __restrict__ xsraw,
             unsigned short* __restrict__ bcraw){
  __shared__ __align__(16) unsigned short lA[128*64];
  __shared__ __align__(16) unsigned short lB[128*64];
  const int t = threadIdx.x;
  const int row0 = blockIdx.y * 128, col0 = blockIdx.x * 128;
  floatx4 acc[4][4] = {};
  gemm_core(A, B, DIMK, row0, col0, lA, lB, acc, t);
  const int w = t >> 6, lane = t & 63, quad = lane >> 4, l16 = lane & 15;
  const int wr = (w >> 1) * 64, wc = (w & 1) * 64;
  unsigned short* dst; int cbase, ldd;
  if (col0 < 4096){ dst = zbuf; cbase = 0; ldd = 4096; }
  else if (col0 < 8192){ dst = xsraw; cbase = 4096; ldd = 4096; }
  else { dst = bcraw; cbase = 8192; ldd = 256; }
#pragma unroll
  for (int i = 0; i < 4; i++)
#pragma unroll
    for (int j = 0; j < 4; j++){
      int rb = row0 + wr + i*16 + quad*4;
      int cc = col0 + wc + j*16 + l16 - cbase;
#pragma unroll
      for (int r = 0; r < 4; r++)
        dst[(size_t)(rb + r) * ldd + cc] = f2h(acc[i][j][r]);
    }
}

// ---------------- GEMM2: fp32 epilogue to d_out ----------------
__global__ __launch_bounds__(256, 2)
void k_gemm2(const unsigned short* __restrict__ A, const unsigned short* __restrict__ B,
             float* __restrict__ C){
  __shared__ __align__(16) unsigned short lA[128*64];
  __shared__ __align__(16) unsigned short lB[128*64];
  const int t = threadIdx.x;
  const int row0 = blockIdx.y * 128, col0 = blockIdx.x * 128;
  floatx4 acc[4][4] = {};
  gemm_core(A, B, HIDN, row0, col0, lA, lB, acc, t);
  const int w = t >> 6, lane = t & 63, quad = lane >> 4, l16 = lane & 15;
  const int wr = (w >> 1) * 64, wc = (w & 1) * 64;
#pragma unroll
  for (int i = 0; i < 4; i++)
#pragma unroll
    for (int j = 0; j < 4; j++){
      int rb = row0 + wr + i*16 + quad*4;
      int cc = col0 + wc + j*16 + l16;
#pragma unroll
      for (int r = 0; r < 4; r++)
        C[(size_t)(rb + r) * DIMK + cc] = acc[i][j][r];
    }
}

// ---------------- extract pre-conv xs halo rows (3 per chunk boundary) ----------------
// slot s holds row bc*128 - 3 + s
__global__ void k_halo(const unsigned short* __restrict__ xsraw, unsigned short* __restrict__ halo){
  int col = blockIdx.x * 256 + threadIdx.x;   // [0,4096)
  int slot = blockIdx.y, bc = blockIdx.z;
  long r = (long)bc * QCH - 3 + slot;
  if (r >= 0)
    halo[((size_t)bc * 3 + slot) * 4096 + col] = xsraw[(size_t)r * 4096 + col];
}

// ---------------- causal conv (K=4) + SiLU on B/C columns only ----------------
__global__ void k_convbc(const unsigned short* __restrict__ bcraw, const float* __restrict__ cw,
                         unsigned short* __restrict__ bcc){
  int row = blockIdx.x, c = threadIdx.x;      // c in [0,256)
  int tl = row & 4095;
  const float4 wv = *(const float4*)&cw[(size_t)(4096 + c) * 4];
  const unsigned short* col = bcraw + c;
  size_t rb = (size_t)row * 256;
  float a = h2f(col[rb]) * wv.w;
  if (tl >= 1) a += h2f(col[rb - 256]) * wv.z;
  if (tl >= 2) a += h2f(col[rb - 512]) * wv.y;
  if (tl >= 3) a += h2f(col[rb - 768]) * wv.x;
  bcc[rb + c] = f2h(a / (1.f + __expf(-a)));
}

// ---------------- softplus(dt) + per-chunk cumsum of dt*A ----------------
__global__ void k_dtcum(const float* __restrict__ dtraw, const float* __restrict__ dtbias,
                        const float* __restrict__ Alog, float* __restrict__ dtb,
                        float* __restrict__ cumb){
  int bc = blockIdx.x;        // [0,64)
  int h  = threadIdx.x;       // [0,64)
  float bias = dtbias[h];
  float A = -__expf(Alog[h]);
  float run = 0.f;
  size_t rowb = (size_t)bc * QCH;
  for (int q = 0; q < QCH; q++){
    float dr = dtraw[(rowb + q) * 64 + h] + bias;
    float dt = dr > 20.f ? dr : log1pf(__expf(dr));
    dtb[(rowb + q) * 64 + h] = dt;
    run += dt * A;
    cumb[(rowb + q) * 64 + h] = run;
  }
}

// ---------------- fused conv+SiLU staging of xs tile, transposed (P x Q) ----------------
// tap t-k, row rowb+q-k: in-chunk if q>=k, else halo slot (q-k+3)
__device__ inline void stage_xsT(const unsigned short* __restrict__ xsraw,
                                 const unsigned short* __restrict__ halo,
                                 const float* cws, unsigned short* xsT,
                                 int bc, int h, int t){
  const size_t rowb = (size_t)bc * QCH;
  const int tl0 = (bc & 31) * QCH;
#pragma unroll
  for (int it = 0; it < 2; it++){
    int idx = it * 256 + t;
    int q = idx & 127, p0 = (idx >> 7) * 16;
    int tl = tl0 + q;
    const unsigned short* cur = xsraw + (rowb + q) * 4096 + h * 64 + p0;
    const unsigned short* hb  = halo + ((size_t)bc * 3) * 4096 + h * 64 + p0;
    const unsigned short* r1 = (q >= 1) ? cur - 4096     : hb + 2 * 4096;
    const unsigned short* r2 = (q >= 2) ? cur - 2 * 4096 : hb + (size_t)(q + 1) * 4096;
    const unsigned short* r3 = (q >= 3) ? cur - 3 * 4096 : hb + (size_t)q * 4096;
    float f1 = (tl >= 1) ? 1.f : 0.f;
    float f2 = (tl >= 2) ? 1.f : 0.f;
    float f3 = (tl >= 3) ? 1.f : 0.f;
    short8 c0 = *(const short8*)cur, c1 = *(const short8*)(cur + 8);
    short8 a0 = *(const short8*)r1,  a1 = *(const short8*)(r1 + 8);
    short8 b0 = *(const short8*)r2,  b1 = *(const short8*)(r2 + 8);
    short8 d0 = *(const short8*)r3,  d1 = *(const short8*)(r3 + 8);
#pragma unroll
    for (int j = 0; j < 16; j++){
      int col = p0 + j;
      const float* wp = cws + col * 4;
      float vc = h2f((unsigned short)(j < 8 ? c0[j] : c1[j-8]));
      float v1 = h2f((unsigned short)(j < 8 ? a0[j] : a1[j-8]));
      float v2 = h2f((unsigned short)(j < 8 ? b0[j] : b1[j-8]));
      float v3 = h2f((unsigned short)(j < 8 ? d0[j] : d1[j-8]));
      float a = vc * wp[3] + f1 * v1 * wp[2] + f2 * v2 * wp[1] + f3 * v3 * wp[0];
      float s = a / (1.f + __expf(-a));
      xsT[col * 128 + q] = f2h(s);
    }
  }
}

// ---------------- per-(chunk,head): CB -> M -> Yd; + Yoff from Sprev; y = Yd+Yoff+D*xs ----------------
__global__ __launch_bounds__(256, 2)
void k_chunk1(const unsigned short* __restrict__ xsraw, const unsigned short* __restrict__ bcc,
              const unsigned short* __restrict__ halo, const float* __restrict__ cw,
              const float* __restrict__ dtb, const float* __restrict__ cumb,
              const float* __restrict__ Dp, const unsigned short* __restrict__ st,
              unsigned short* __restrict__ ybuf){
  __shared__ __align__(16) unsigned short Ml[128*128];
  __shared__ __align__(16) unsigned short xsT[64*128];
  __shared__ float cum_s[128], dt_s[128];
  __shared__ float cws[64*4];
  const int blk = blockIdx.x, h = blk & 63, bc = blk >> 6;
  const size_t rowb = (size_t)bc * QCH;
  const int t = threadIdx.x, w = t >> 6, lane = t & 63, quad = lane >> 4, l16 = lane & 15;
  const int wrow = w * 32;
  if (t < 128){ cum_s[t] = cumb[(rowb + t)*64 + h]; dt_s[t] = dtb[(rowb + t)*64 + h]; }
  if (t < 64) *(float4*)&cws[t*4] = *(const float4*)&cw[((size_t)h*64 + t)*4];
  __syncthreads();
  stage_xsT(xsraw, halo, cws, xsT, bc, h, t);
  // CB = C @ B^T from post-conv bcc
  floatx4 acc[2][8] = {};
  const unsigned short* Cb = bcc + rowb * 256 + 128;
  const unsigned short* Bb = bcc + rowb * 256;
#pragma unroll
  for (int ks = 0; ks < 4; ks++){
    half8 af[2];
#pragma unroll
    for (int i = 0; i < 2; i++)
      af[i] = *(const half8*)(Cb + (size_t)(wrow + i*16 + l16) * 256 + ks*32 + quad*8);
#pragma unroll
    for (int j = 0; j < 8; j++){
      half8 bfr = *(const half8*)(Bb + (size_t)(j*16 + l16) * 256 + ks*32 + quad*8);
#pragma unroll
      for (int i = 0; i < 2; i++)
        acc[i][j] = __builtin_amdgcn_mfma_f32_16x16x32_f16(af[i], bfr, acc[i][j], 0, 0, 0);
    }
  }
  // M = CB * exp(cum_i - cum_j) * dt_j, causal, -> LDS fp16
#pragma unroll
  for (int i = 0; i < 2; i++)
#pragma unroll
    for (int j = 0; j < 8; j++){
      int jc = j*16 + l16;
      float dtj = dt_s[jc], cj = cum_s[jc];
#pragma unroll
      for (int r = 0; r < 4; r++){
        int ir = wrow + i*16 + quad*4 + r;
        float m = (ir >= jc) ? acc[i][j][r] * __expf(cum_s[ir] - cj) * dtj : 0.f;
        Ml[ir * 128 + jc] = f2h(m);
      }
    }
  __syncthreads();
  // Yd = M @ xs
  floatx4 accY[2][4] = {};
#pragma unroll
  for (int ks = 0; ks < 4; ks++){
    half8 af[2], bfr[4];
#pragma unroll
    for (int i = 0; i < 2; i++)
      af[i] = *(const half8*)&Ml[(wrow + i*16 + l16)*128 + ks*32 + quad*8];
#pragma unroll
    for (int p = 0; p < 4; p++)
      bfr[p] = *(const half8*)&xsT[(p*16 + l16)*128 + ks*32 + quad*8];
#pragma unroll
    for (int i = 0; i < 2; i++)
#pragma unroll
      for (int p = 0; p < 4; p++)
        accY[i][p] = __builtin_amdgcn_mfma_f32_16x16x32_f16(af[i], bfr[p], accY[i][p], 0, 0, 0);
  }
  // ---- Yoff: stage Sprev (fp16) into Ml's LDS, then C @ Sprev^T ----
  __syncthreads();                       // all Yd reads of Ml done
  unsigned short* Sp = Ml;               // reuse (64*128 <= 128*128)
  {
    size_t base = ((size_t)bc * 64 + h) * 8192;
#pragma unroll
    for (int it = 0; it < 4; it++){
      int idx = (it * 256 + t) * 8;
      *(short8*)&Sp[idx] = *(const short8*)&st[base + idx];
    }
  }
  __syncthreads();
  floatx4 accO[2][4] = {};
#pragma unroll
  for (int ks = 0; ks < 4; ks++){
    half8 af[2], bfr[4];
#pragma unroll
    for (int i = 0; i < 2; i++)
      af[i] = *(const half8*)(Cb + (size_t)(wrow + i*16 + l16) * 256 + ks*32 + quad*8);
#pragma unroll
    for (int p = 0; p < 4; p++)
      bfr[p] = *(const half8*)&Sp[(p*16 + l16)*128 + ks*32 + quad*8];
#pragma unroll
    for (int i = 0; i < 2; i++)
#pragma unroll
      for (int p = 0; p < 4; p++)
        accO[i][p] = __builtin_amdgcn_mfma_f32_16x16x32_f16(af[i], bfr[p], accO[i][p], 0, 0, 0);
  }
  float Dh = Dp[h];
#pragma unroll
  for (int i = 0; i < 2; i++)
#pragma unroll
    for (int p = 0; p < 4; p++){
      int pc = p*16 + l16;
#pragma unroll
      for (int r = 0; r < 4; r++){
        int ir = wrow + i*16 + quad*4 + r;
        float y = accY[i][p][r] + __expf(cum_s[ir]) * accO[i][p][r] + Dh * h2f(xsT[pc*128 + ir]);
        ybuf[(rowb + ir) * (size_t)HIDN + h*64 + pc] = f2h(y);
      }
    }
}

// ---------------- per-(chunk,head): states[p][n] = sum_q xs[q][p]*wdec_q*B[q][n] ----------------
__global__ __launch_bounds__(256, 2)
void k_chunk2(const unsigned short* __restrict__ xsraw, const unsigned short* __restrict__ bcc,
              const unsigned short* __restrict__ halo, const float* __restrict__ cw,
              const float* __restrict__ dtb, const float* __restrict__ cumb,
              unsigned short* __restrict__ st){
  __shared__ __align__(16) unsigned short wBT[128*128];
  __shared__ __align__(16) unsigned short xsT[64*128];
  __shared__ float cum_s[128], dt_s[128];
  __shared__ float cws[64*4];
  const int blk = blockIdx.x, h = blk & 63, bc = blk >> 6;
  const size_t rowb = (size_t)bc * QCH;
  const int t = threadIdx.x, w = t >> 6, lane = t & 63, quad = lane >> 4, l16 = lane & 15;
  if (t < 128){ cum_s[t] = cumb[(rowb + t)*64 + h]; dt_s[t] = dtb[(rowb + t)*64 + h]; }
  if (t < 64) *(float4*)&cws[t*4] = *(const float4*)&cw[((size_t)h*64 + t)*4];
  __syncthreads();
  stage_xsT(xsraw, halo, cws, xsT, bc, h, t);
  float clast = cum_s[127];
#pragma unroll
  for (int it = 0; it < 2; it++){                 // wBT[n][q] = B[q][n]*wdec_q
    int idx = it * 256 + t;
    int q = idx & 127, n0 = (idx >> 7) * 32;
    float wd = __expf(clast - cum_s[q]) * dt_s[q];
    const unsigned short* gp = bcc + (rowb + q) * 256 + n0;
#pragma unroll
    for (int c4 = 0; c4 < 4; c4++){
      short8 v = *(const short8*)(gp + c4*8);
#pragma unroll
      for (int jj = 0; jj < 8; jj++)
        wBT[(n0 + c4*8 + jj)*128 + q] = f2h(h2f((unsigned short)v[jj]) * wd);
    }
  }
  __syncthreads();
  floatx4 acc[8] = {};
#pragma unroll
  for (int ks = 0; ks < 4; ks++){
    half8 af = *(const half8*)&xsT[(w*16 + l16)*128 + ks*32 + quad*8];
#pragma unroll
    for (int j = 0; j < 8; j++){
      half8 bfr = *(const half8*)&wBT[(j*16 + l16)*128 + ks*32 + quad*8];
      acc[j] = __builtin_amdgcn_mfma_f32_16x16x32_f16(af, bfr, acc[j], 0, 0, 0);
    }
  }
  size_t base = ((size_t)bc * 64 + h) * 8192;
#pragma unroll
  for (int j = 0; j < 8; j++){
    int n = j*16 + l16;
#pragma unroll
    for (int r = 0; r < 4; r++){
      int p = w*16 + quad*4 + r;
      st[base + p*128 + n] = f2h(acc[j][r]);
    }
  }
}

// ---------------- sequential inter-chunk scan (fp16 states -> Sprev, in place) ----------------
__global__ void k_scan(unsigned short* __restrict__ st, const float* __restrict__ cumb){
  int id = blockIdx.x * 256 + threadIdx.x;  // [0, 2*64*64*128)
  int n = id & 127, p = (id >> 7) & 63, h = (id >> 13) & 63, b = id >> 19;
  float S = 0.f;
  for (int c = 0; c < NCHUNK; c++){
    int bc = b * NCHUNK + c;
    size_t idx = ((size_t)bc * 64 + h) * 8192 + (size_t)p * 128 + n;
    float dec = __expf(cumb[((size_t)bc * QCH + 127) * 64 + h]);
    float v = h2f(st[idx]);
    st[idx] = f2h(S);
    S = S * dec + v;
  }
}

// ---------------- gate y*silu(z) + RMSNorm, in-place fp16 ----------------
__global__ __launch_bounds__(256)
void k_gate(unsigned short* __restrict__ yb, const unsigned short* __restrict__ zb,
            const float* __restrict__ nw){
  __shared__ float red[4];
  int row = blockIdx.x, t = threadIdx.x;
  float vals[16], ss = 0.f;
#pragma unroll
  for (int it = 0; it < 16; it++){
    int c = it * 256 + t;
    float y = h2f(yb[(size_t)row * HIDN + c]);
    float z = h2f(zb[(size_t)row * HIDN + c]);
    float v = y * (z / (1.f + __expf(-z)));
    vals[it] = v; ss += v * v;
  }
  for (int o = 32; o > 0; o >>= 1) ss += __shfl_down(ss, o, 64);
  int w = t >> 6, lane = t & 63;
  if (lane == 0) red[w] = ss;
  __syncthreads();
  float scale = rsqrtf((red[0] + red[1] + red[2] + red[3]) / (float)HIDN + 1e-5f);
#pragma unroll
  for (int it = 0; it < 16; it++){
    int c = it * 256 + t;
    yb[(size_t)row * HIDN + c] = f2h(vals[it] * scale * nw[c]);
  }
}

extern "C" void kernel_launch(void* const* d_in, const int* in_sizes, int n_in,
                              void* d_out, int out_size, void* d_ws, size_t ws_size,
                              hipStream_t stream){
  const float* x      = (const float*)d_in[0];
  const float* Win    = (const float*)d_in[1];
  const float* convw  = (const float*)d_in[2];
  const float* dtbias = (const float*)d_in[3];
  const float* Alog   = (const float*)d_in[4];
  const float* Dp     = (const float*)d_in[5];
  const float* nw     = (const float*)d_in[6];
  const float* Wout   = (const float*)d_in[7];
  float* out = (float*)d_out;

  char* ws = (char*)d_ws;
  size_t off = 0;
  auto alloc = [&](size_t bytes)->void*{ void* p = ws + off; off += (bytes + 255) & ~(size_t)255; return p; };
  unsigned short* xw    = (unsigned short*)alloc((size_t)ROWS * DIMK * 2);   // 33.5 MB (dead after gemm1)
  unsigned short* winb  = (unsigned short*)alloc((size_t)8448 * DIMK * 2);   // 34.6 MB (dead after gemm1)
  float*          dtraw = (float*)alloc((size_t)ROWS * 64 * 4);              // 2.1 MB
  unsigned short* woutb = (unsigned short*)alloc((size_t)DIMK * HIDN * 2);   // 16.8 MB
  unsigned short* zbuf  = (unsigned short*)alloc((size_t)ROWS * HIDN * 2);   // 67.1 MB
  unsigned short* xsraw = (unsigned short*)alloc((size_t)ROWS * HIDN * 2);   // 67.1 MB (becomes ybuf/yn)
  unsigned short* bcraw = (unsigned short*)alloc((size_t)ROWS * 256 * 2);    // 4.2 MB
  unsigned short* bcc   = (unsigned short*)alloc((size_t)ROWS * 256 * 2);    // 4.2 MB
  unsigned short* halo  = (unsigned short*)alloc((size_t)64 * 3 * 4096 * 2); // 1.5 MB
  float*          dtb   = (float*)alloc((size_t)ROWS * 64 * 4);              // 2.1 MB
  float*          cumb  = (float*)alloc((size_t)ROWS * 64 * 4);              // 2.1 MB
  // total ~224.5 MiB; states (fp16, 67.1 MB) overlays dead xw+winb region
  unsigned short* st    = xw;
  unsigned short* ybuf  = xsraw;   // chunk1 writes y in-place over pre-conv xs (chunk2 ran first)

  k_cast<<<(ROWS*DIMK/4 + 255)/256, 256, 0, stream>>>(x, xw, ROWS*DIMK/4);
  k_cast<<<(8448*DIMK/4 + 255)/256, 256, 0, stream>>>(Win, winb, 8448*DIMK/4);
  k_cast<<<(DIMK*HIDN/4 + 255)/256, 256, 0, stream>>>(Wout, woutb, DIMK*HIDN/4);
  k_dtraw<<<ROWS/8, 256, 0, stream>>>(x, Win, dtraw);
  k_gemm1<<<dim3(66, ROWS/128), 256, 0, stream>>>(xw, winb, zbuf, xsraw, bcraw);
  k_halo<<<dim3(16, 3, 64), 256, 0, stream>>>(xsraw, halo);
  k_convbc<<<ROWS, 256, 0, stream>>>(bcraw, convw, bcc);
  k_dtcum<<<64, 64, 0, stream>>>(dtraw, dtbias, Alog, dtb, cumb);
  k_chunk2<<<4096, 256, 0, stream>>>(xsraw, bcc, halo, convw, dtb, cumb, st);
  k_scan<<<4096, 256, 0, stream>>>(st, cumb);
  k_chunk1<<<4096, 256, 0, stream>>>(xsraw, bcc, halo, convw, dtb, cumb, Dp, st, ybuf);
  k_gate<<<ROWS, 256, 0, stream>>>(ybuf, zbuf, nw);
  k_gemm2<<<dim3(16, ROWS/128), 256, 0, stream>>>(ybuf, woutb, out);
}